// Round 3
// baseline (49.381 us; speedup 1.0000x reference)
//
#include <hip/hip_runtime.h>

constexpr int T_TOTAL = 100000;
constexpr int RANK    = 128;
constexpr int W       = 11;
constexpr int PAD     = 5;      // (W-1)/2
constexpr int BLOCK   = 256;
constexpr int T_PER_BLOCK = 16; // 4 waves x 4 groups, one t per 16-lane group

// 16-lane sum+broadcast butterfly on the VALU pipe (DPP).
// 0xB1 quad_perm xor1, 0x4E quad_perm xor2, 0x141 row_half_mirror, 0x140 row_mirror.
template <int CTRL>
__device__ __forceinline__ float dpp_radd(float v) {
    int o = __builtin_amdgcn_update_dpp(0, __float_as_int(v), CTRL, 0xF, 0xF, true);
    return v + __int_as_float(o);
}

__global__ __launch_bounds__(BLOCK) void attn_win_kernel(const float* __restrict__ in,
                                                         float* __restrict__ out) {
    const int tid  = threadIdx.x;
    const int wave = tid >> 6;
    const int lane = tid & 63;
    const int g    = lane >> 4;
    const int sub  = lane & 15;

    // one t per 16-lane group; groups in a wave own consecutive t -> wave loads are
    // contiguous 2KB (lane*32B) global transactions
    const int t = blockIdx.x * T_PER_BLOCK + wave * 4 + g;   // always < T_TOTAL (6250*16)
    const float* xp = in + (size_t)t * RANK + sub * 8;

    const float4 x0 = *reinterpret_cast<const float4*>(xp);
    const float4 x1 = *reinterpret_cast<const float4*>(xp + 4);

    constexpr float LOG2E = 1.4426950408889634f;
    float m   = -1e30f;
    float sum = 0.f;
    float acc[8] = {0.f, 0.f, 0.f, 0.f, 0.f, 0.f, 0.f, 0.f};

    #pragma unroll
    for (int j = 0; j < W; ++j) {
        float4 b0, b1;
        if (j == PAD) {                       // window row 5 IS row t
            b0 = x0; b1 = x1;
        } else {
            const int row = t + j - PAD;
            b0 = make_float4(0.f, 0.f, 0.f, 0.f);
            b1 = make_float4(0.f, 0.f, 0.f, 0.f);
            if ((unsigned)row < (unsigned)T_TOTAL) {
                const float* bp = in + (size_t)row * RANK + sub * 8;
                b0 = *reinterpret_cast<const float4*>(bp);
                b1 = *reinterpret_cast<const float4*>(bp + 4);
            }
        }

        float s = b0.x * x0.x + b0.y * x0.y + b0.z * x0.z + b0.w * x0.w
                + b1.x * x1.x + b1.y * x1.y + b1.z * x1.z + b1.w * x1.w;
        // 16-lane reduce+broadcast on VALU
        s = dpp_radd<0xB1>(s);
        s = dpp_radd<0x4E>(s);
        s = dpp_radd<0x141>(s);
        s = dpp_radd<0x140>(s);
        s *= LOG2E;                            // exp2 domain

        const float mn   = fmaxf(m, s);
        const float corr = exp2f(m - mn);      // first iter: 0
        const float w    = exp2f(s - mn);
        m   = mn;
        sum = sum * corr + w;
        acc[0] = fmaf(acc[0], corr, w * b0.x);
        acc[1] = fmaf(acc[1], corr, w * b0.y);
        acc[2] = fmaf(acc[2], corr, w * b0.z);
        acc[3] = fmaf(acc[3], corr, w * b0.w);
        acc[4] = fmaf(acc[4], corr, w * b1.x);
        acc[5] = fmaf(acc[5], corr, w * b1.y);
        acc[6] = fmaf(acc[6], corr, w * b1.z);
        acc[7] = fmaf(acc[7], corr, w * b1.w);
    }

    const float inv = 1.f / sum;
    float* op = out + (size_t)t * RANK + sub * 8;
    *reinterpret_cast<float4*>(op) =
        make_float4(acc[0] * inv, acc[1] * inv, acc[2] * inv, acc[3] * inv);
    *reinterpret_cast<float4*>(op + 4) =
        make_float4(acc[4] * inv, acc[5] * inv, acc[6] * inv, acc[7] * inv);
}

extern "C" void kernel_launch(void* const* d_in, const int* in_sizes, int n_in,
                              void* d_out, int out_size, void* d_ws, size_t ws_size,
                              hipStream_t stream) {
    const float* in  = (const float*)d_in[0];
    float*       out = (float*)d_out;
    const int grid = T_TOTAL / T_PER_BLOCK;   // 6250, exact
    attn_win_kernel<<<grid, BLOCK, 0, stream>>>(in, out);
}